// Round 1
// baseline (730.796 us; speedup 1.0000x reference)
//
#include <hip/hip_runtime.h>
#include <cstdint>
#include <cstddef>

#define B_  4
#define S_  2048
#define D_  1024
#define H_  16
#define HD_ 64
#define M_  (B_ * S_)   // 8192 rows

typedef __bf16 bf16_t;
typedef bf16_t bf16x8 __attribute__((ext_vector_type(8)));
typedef float  floatx4 __attribute__((ext_vector_type(4)));

// ---------------------------------------------------------------------------
// async 16B global -> LDS copy (gfx950). LDS dest must be wave-uniform base +
// lane*16 in issue order (m104/m108 caveat) — our staging layout guarantees it.
// ---------------------------------------------------------------------------
__device__ __forceinline__ void async_copy16(const void* gmem, void* lds) {
  __builtin_amdgcn_global_load_lds(
      (__attribute__((address_space(1))) void*)const_cast<void*>(gmem),
      (__attribute__((address_space(3))) void*)lds,
      16, 0, 0);
}

// ---------------------------------------------------------------------------
// Weight fp32 -> bf16 cast, 4 matrices of 1M elems each, contiguous output.
// ---------------------------------------------------------------------------
__global__ void cast_w_kernel(const float* __restrict__ w0, const float* __restrict__ w1,
                              const float* __restrict__ w2, const float* __restrict__ w3,
                              bf16_t* __restrict__ out) {
  int idx = blockIdx.x * blockDim.x + threadIdx.x;   // 0 .. 4M-1
  const int ONE_M = 1 << 20;
  const float* src = (idx < ONE_M) ? w0 : (idx < 2 * ONE_M) ? w1 : (idx < 3 * ONE_M) ? w2 : w3;
  out[idx] = (bf16_t)src[idx & (ONE_M - 1)];
}

// ---------------------------------------------------------------------------
// Token-shift mix: xr/xk/xv = x*m + shift(x)*(1-m), bf16 outputs.
// ---------------------------------------------------------------------------
__global__ void mix_kernel(const float* __restrict__ x,
                           const float* __restrict__ tmr, const float* __restrict__ tmk,
                           const float* __restrict__ tmv,
                           bf16_t* __restrict__ xr, bf16_t* __restrict__ xk,
                           bf16_t* __restrict__ xv) {
  int idx = blockIdx.x * blockDim.x + threadIdx.x;   // 0 .. 8M-1
  int d = idx & (D_ - 1);
  int t = (idx / D_) & (S_ - 1);
  float xc = x[idx];
  float xp = (t == 0) ? 0.0f : x[idx - D_];
  float mr = tmr[d], mk = tmk[d], mv = tmv[d];
  xr[idx] = (bf16_t)(xc * mr + xp * (1.0f - mr));
  xk[idx] = (bf16_t)(xc * mk + xp * (1.0f - mk));
  xv[idx] = (bf16_t)(xc * mv + xp * (1.0f - mv));
}

// ---------------------------------------------------------------------------
// C[M,N] = A[M,K] * B[N,K]^T, bf16 in / fp32 out. 128x128 tile, BK=32,
// 4 waves each computing 64x64 via 4x4 of 16x16x32 MFMA. m97 structure.
// ---------------------------------------------------------------------------
__global__ __launch_bounds__(256)
void gemm_bt(const bf16_t* __restrict__ A, const bf16_t* __restrict__ Bw,
             float* __restrict__ C, int M, int N, int K) {
  constexpr int BM = 128, BN = 128, BK = 32;
  __shared__ __align__(16) bf16_t As[BM][BK];   // 8 KB
  __shared__ __align__(16) bf16_t Bs[BN][BK];   // 8 KB

  const int tid  = threadIdx.x;
  const int lane = tid & 63;
  const int wave = tid >> 6;
  const int wm   = wave >> 1;      // 0..1
  const int wn   = wave & 1;       // 0..1
  const int l15  = lane & 15;
  const int quad = lane >> 4;      // 0..3

  const int n0 = blockIdx.x * BN;
  const int m0 = blockIdx.y * BM;

  floatx4 acc[4][4] = {};

  // staging: chunk c = i*256 + tid covers 16B at LDS offset c*16;
  // row = c>>2 (64B per row of BK=32 bf16), byte-in-row = (c&3)*16.
  const int row0 = tid >> 2;
  const int colb = (tid & 3) * 16;

  const char* Abase = (const char*)(A + (size_t)m0 * K);
  const char* Bbase = (const char*)(Bw + (size_t)n0 * K);
  char* AsB = (char*)&As[0][0];
  char* BsB = (char*)&Bs[0][0];
  const size_t rowpitch = (size_t)K * 2;

  for (int kb = 0; kb < K; kb += BK) {
#pragma unroll
    for (int i = 0; i < 2; ++i) {
      int r = row0 + i * 64;
      int lo = r * 64 + colb;
      async_copy16(Abase + (size_t)r * rowpitch + (size_t)kb * 2 + colb, AsB + lo);
      async_copy16(Bbase + (size_t)r * rowpitch + (size_t)kb * 2 + colb, BsB + lo);
    }
    __syncthreads();   // drains vmcnt(0) then barrier

    bf16x8 afrag[4], bfrag[4];
#pragma unroll
    for (int i = 0; i < 4; ++i) {
      afrag[i] = *(const bf16x8*)&As[wm * 64 + i * 16 + l15][quad * 8];
      bfrag[i] = *(const bf16x8*)&Bs[wn * 64 + i * 16 + l15][quad * 8];
    }
#pragma unroll
    for (int i = 0; i < 4; ++i)
#pragma unroll
      for (int j = 0; j < 4; ++j)
        acc[i][j] = __builtin_amdgcn_mfma_f32_16x16x32_bf16(afrag[i], bfrag[j], acc[i][j], 0, 0, 0);
    __syncthreads();
  }

  // C/D layout (m89-verified): col = lane&15, row = quad*4 + reg
#pragma unroll
  for (int i = 0; i < 4; ++i) {
#pragma unroll
    for (int j = 0; j < 4; ++j) {
      int row = m0 + wm * 64 + i * 16 + quad * 4;
      int col = n0 + wn * 64 + j * 16 + l15;
      float* Cp = C + (size_t)row * N + col;
#pragma unroll
      for (int r = 0; r < 4; ++r)
        Cp[(size_t)r * N] = acc[i][j][r];
    }
  }
}

// ---------------------------------------------------------------------------
// WKV scan: one wave per (b,h), lane = hd. Reference recurrence verbatim.
// Fuses sigmoid(r)*wkv and GroupNorm sum/sumsq stats.
// ---------------------------------------------------------------------------
__global__ __launch_bounds__(64)
void wkv_scan(const float* __restrict__ rbuf, const float* __restrict__ kbuf,
              const float* __restrict__ vbuf,
              const float* __restrict__ time_decay, const float* __restrict__ time_first,
              float* __restrict__ rwkv, float* __restrict__ stats) {
  const int bh = blockIdx.x;           // 0..63
  const int b = bh / H_, h = bh % H_;
  const int lane = threadIdx.x;        // 0..63 == hd
  const int c = h * HD_ + lane;        // channel within D

  const float w = -__expf(time_decay[c]);
  const float u = time_first[c];

  size_t idx = (size_t)b * S_ * D_ + c;

  float a = 0.0f, bst = -1e38f;
  float sum = 0.0f, sumsq = 0.0f;

  float kt = kbuf[idx], vt = vbuf[idx], rt = rbuf[idx];
  for (int t = 0; t < S_; ++t) {
    float kn = 0.0f, vn = 0.0f, rn = 0.0f;
    if (t + 1 < S_) {                   // wave-uniform; prefetch next step
      size_t nidx = idx + D_;
      kn = kbuf[nidx]; vn = vbuf[nidx]; rn = rbuf[nidx];
    }
    float wk = kt + u;
    float p  = fmaxf(bst, wk);
    float e1 = __expf(bst - p);
    float e2 = __expf(wk - p);
    float out = (e1 * a + e2 * vt) / (e1 + e2 + 1e-8f);

    float ww = bst + w;
    float p2 = fmaxf(ww, kt);
    float e1b = __expf(ww - p2);
    float e2b = __expf(kt - p2);
    a   = e1b * a + e2b * vt;
    bst = p2 + __logf(e1b + e2b + 1e-8f);

    float sig = 1.0f / (1.0f + __expf(-rt));
    float o = sig * out;
    rwkv[idx] = o;
    sum += o; sumsq += o * o;

    idx += D_;
    kt = kn; vt = vn; rt = rn;
  }

  // wave-level reduce (64 lanes) for GroupNorm stats over (s, hd)
#pragma unroll
  for (int off = 32; off > 0; off >>= 1) {
    sum   += __shfl_down(sum, off);
    sumsq += __shfl_down(sumsq, off);
  }
  if (lane == 0) {
    const float n = (float)(S_ * HD_);
    float mean = sum / n;
    float var  = sumsq / n - mean * mean;
    stats[2 * bh]     = mean;
    stats[2 * bh + 1] = rsqrtf(var + 1e-5f);
  }
}

// ---------------------------------------------------------------------------
// GroupNorm apply + bf16 cast for the output projection.
// ---------------------------------------------------------------------------
__global__ void norm_cast(const float* __restrict__ rwkv, const float* __restrict__ stats,
                          const float* __restrict__ gamma, const float* __restrict__ beta,
                          bf16_t* __restrict__ normed) {
  int idx = blockIdx.x * blockDim.x + threadIdx.x;   // 0 .. 8M-1
  int d = idx & (D_ - 1);
  int h = d >> 6;
  int b = idx / (S_ * D_);
  int bh = b * H_ + h;
  float mean = stats[2 * bh];
  float rstd = stats[2 * bh + 1];
  float v = (rwkv[idx] - mean) * rstd * gamma[d] + beta[d];
  normed[idx] = (bf16_t)v;
}

// ---------------------------------------------------------------------------
extern "C" void kernel_launch(void* const* d_in, const int* in_sizes, int n_in,
                              void* d_out, int out_size, void* d_ws, size_t ws_size,
                              hipStream_t stream) {
  const float* x     = (const float*)d_in[0];
  const float* tmr   = (const float*)d_in[1];
  const float* tmk   = (const float*)d_in[2];
  const float* tmv   = (const float*)d_in[3];
  const float* Wr    = (const float*)d_in[4];
  const float* Wk    = (const float*)d_in[5];
  const float* Wv    = (const float*)d_in[6];
  const float* Wo    = (const float*)d_in[7];
  const float* td    = (const float*)d_in[8];
  const float* tf    = (const float*)d_in[9];
  const float* gamma = (const float*)d_in[10];
  const float* beta  = (const float*)d_in[11];

  char* ws = (char*)d_ws;
  const size_t MB = 1024 * 1024;
  bf16_t* W_bf   = (bf16_t*)(ws + 0 * MB);     // 4 x 2MB contiguous
  bf16_t* Wr_bf  = (bf16_t*)(ws + 0 * MB);
  bf16_t* Wk_bf  = (bf16_t*)(ws + 2 * MB);
  bf16_t* Wv_bf  = (bf16_t*)(ws + 4 * MB);
  bf16_t* Wo_bf  = (bf16_t*)(ws + 6 * MB);
  bf16_t* xr     = (bf16_t*)(ws + 8 * MB);     // 16MB each
  bf16_t* xk     = (bf16_t*)(ws + 24 * MB);
  bf16_t* xv     = (bf16_t*)(ws + 40 * MB);
  float*  rbuf   = (float*)(ws + 56 * MB);     // 32MB each
  float*  kbuf   = (float*)(ws + 88 * MB);
  float*  vbuf   = (float*)(ws + 120 * MB);
  float*  stats  = (float*)(ws + 152 * MB);    // 64 * 2 floats
  bf16_t* normed = xr;                         // xr dead after GEMM #1

  float* rwkv = (float*)d_out;                 // d_out doubles as fp32 scratch
  float* outp = (float*)d_out;

  cast_w_kernel<<<(4 * 1024 * 1024) / 256, 256, 0, stream>>>(Wr, Wk, Wv, Wo, W_bf);
  mix_kernel<<<(M_ * D_) / 256, 256, 0, stream>>>(x, tmr, tmk, tmv, xr, xk, xv);

  dim3 gg(D_ / 128, M_ / 128);   // (8, 64)
  gemm_bt<<<gg, 256, 0, stream>>>(xr, Wr_bf, rbuf, M_, D_, D_);
  gemm_bt<<<gg, 256, 0, stream>>>(xk, Wk_bf, kbuf, M_, D_, D_);
  gemm_bt<<<gg, 256, 0, stream>>>(xv, Wv_bf, vbuf, M_, D_, D_);

  wkv_scan<<<B_ * H_, 64, 0, stream>>>(rbuf, kbuf, vbuf, td, tf, rwkv, stats);
  norm_cast<<<(M_ * D_) / 256, 256, 0, stream>>>(rwkv, stats, gamma, beta, normed);

  gemm_bt<<<gg, 256, 0, stream>>>(normed, Wo_bf, outp, M_, D_, D_);
}